// Round 9
// baseline (961.803 us; speedup 1.0000x reference)
//
#include <hip/hip_runtime.h>
#include <cmath>

// Problem constants: V=50000, E=300, H=512, L=6, N=8192, K=4
#define VSZ  50000
#define EDIM 300
#define EPAD 320      // E padded to multiple of 32
#define HDIM 512
#define LVLS 6
#define NN   8192
#define KCH  4

// MFMA GEMM: 128x128 block, BK=32 double-buffered, 4 waves of 64x64
#define BM 128
#define BN 128

typedef __attribute__((ext_vector_type(8))) short bf16x8;
typedef __attribute__((ext_vector_type(8))) unsigned short us8;
typedef __attribute__((ext_vector_type(4))) float f32x4;

__device__ __forceinline__ float sigf(float x) { return 1.0f / (1.0f + expf(-x)); }

__device__ __forceinline__ unsigned short f2bf(float f) {
    unsigned u = __float_as_uint(f);
    u += 0x7FFF + ((u >> 16) & 1);           // RNE
    return (unsigned short)(u >> 16);
}
__device__ __forceinline__ float bf2f(unsigned short h) {
    return __uint_as_float(((unsigned)h) << 16);
}

// ---- tiled-swizzled operand layout (BK=32 tiles) -----------------------------
// Matrix [R][Ks] stored as 8 KB tiles of 128 rows x 32 k. Granule = 16 B (8 elem);
// 4 granules/row. Granule at position row*4+slot holds logical k-granule
// slot ^ s(row), s(row) = (row&3)^((row>>2)&3). This swizzle makes the GEMM
// fragment read (16 rows x 4 quads per wave-instr) max 2-way bank-aliased (free,
// m136) AND lets global_load_lds stage it as an identity copy: lane addr =
// tile_base + chunk*16 B -> 1 KB contiguous per wave-instr.
__device__ __forceinline__ size_t tidx(int n, int k, int KT) {
    int row = n & 127;
    int s   = (row & 3) ^ ((row >> 2) & 3);
    int slot = ((k >> 3) & 3) ^ s;
    return ((size_t)(n >> 7) * KT + (k >> 5)) * 4096
         + (size_t)((row * 4 + slot) * 8 + (k & 7));
}

// ---- one-shot weight convert: [W_iou^T|W_f^T] (2048 x EPAD, KT=10) and
// [U_iou^T|U_f^T] (2048 x HDIM, KT=16), bf16 tiled-swizzled ----
__global__ __launch_bounds__(256) void wconv_all_k(
    const float* __restrict__ W_iou, const float* __restrict__ W_f,
    const float* __restrict__ U_iou, const float* __restrict__ U_f,
    unsigned short* __restrict__ Wt, unsigned short* __restrict__ Ut)
{
    const int SW = 2048 * EPAD;
    int t = blockIdx.x * 256 + threadIdx.x;
    if (t < SW) {
        int k = t % EPAD, n = t / EPAD;
        float v = 0.0f;
        if (k < EDIM)
            v = (n < 1536) ? W_iou[(size_t)k * 1536 + n] : W_f[(size_t)k * 512 + (n - 1536)];
        Wt[tidx(n, k, EPAD / 32)] = f2bf(v);
    } else {
        int u = t - SW;
        int k = u % HDIM, n = u / HDIM;
        float v = (n < 1536) ? U_iou[(size_t)k * 1536 + n] : U_f[(size_t)k * 512 + (n - 1536)];
        Ut[tidx(n, k, HDIM / 32)] = f2bf(v);
    }
}

// ---- GEMM body: 128x128 tile, BK=32, double-buffered (2 x (8KB A + 8KB B)).
// Pipeline: stage(kt+1) issued AFTER the barrier guarding stage kt, BEFORE
// compute(kt) -> DMA latency overlaps the 16 MFMA; the vmcnt(0) drain at the
// next barrier waits only the residual. AF32=1: A rows gathered from fp32
// embed, converted in-register, ds_write (same swizzled image). EPI as before.
template <int AF32, int EPI>
__device__ __forceinline__ void gemm_body(
    const unsigned short* __restrict__ At, const float* __restrict__ Af,
    const int* __restrict__ aidx, const float* __restrict__ rowscale,
    const unsigned short* __restrict__ Bt,
    const float* __restrict__ b_iou, const float* __restrict__ b_f,
    unsigned short* __restrict__ C, int ldc, int Ks, int KA,
    int tile_m, int tile_n, unsigned short* smem)
{
    const int tid  = threadIdx.x;
    const int wave = tid >> 6, lane = tid & 63;
    const int quad = lane >> 4, mcol = lane & 15;
    const int wm   = (wave >> 1) * 64, wn = (wave & 1) * 64;
    const int KT   = Ks >> 5;

    unsigned short* AsB = smem;            // [2][4096]
    unsigned short* BsB = smem + 8192;     // [2][4096]

    int agrow[2], kgo[2];
    if (AF32) {
#pragma unroll
        for (int j = 0; j < 2; ++j) {
            int c = tid + 256 * j, row = c >> 2;
            int s = (row & 3) ^ ((row >> 2) & 3);
            kgo[j]   = ((c & 3) ^ s) * 8;
            agrow[j] = aidx[tile_m + row];
        }
    }
    const unsigned short* atile = AF32 ? nullptr
        : At + (size_t)(tile_m >> 7) * KT * 4096;
    const unsigned short* btile = Bt + (size_t)(tile_n >> 7) * KT * 4096;

    f32x4 acc[4][4] = {};

    auto stage = [&](int kt, int buf) {
        unsigned short* Ad = AsB + buf * 4096;
        unsigned short* Bd = BsB + buf * 4096;
        if (AF32) {
#pragma unroll
            for (int j = 0; j < 2; ++j) {
                int e = kt * 32 + kgo[j];
                float4 lo = make_float4(0.f, 0.f, 0.f, 0.f);
                float4 hi = make_float4(0.f, 0.f, 0.f, 0.f);
                const float* sp = Af + (size_t)agrow[j] * KA + e;
                if (e + 4 <= KA) lo = *(const float4*)sp;
                if (e + 8 <= KA) hi = *(const float4*)(sp + 4);
                us8 o;
                o[0] = f2bf(lo.x); o[1] = f2bf(lo.y); o[2] = f2bf(lo.z); o[3] = f2bf(lo.w);
                o[4] = f2bf(hi.x); o[5] = f2bf(hi.y); o[6] = f2bf(hi.z); o[7] = f2bf(hi.w);
                *(us8*)(Ad + (size_t)(tid + 256 * j) * 8) = o;
            }
        } else {
            const unsigned short* ab = atile + (size_t)kt * 4096;
#pragma unroll
            for (int j = 0; j < 2; ++j) {
                __attribute__((address_space(3))) unsigned int* d =
                    (__attribute__((address_space(3))) unsigned int*)(Ad + (wave * 64 + 256 * j) * 8);
                __builtin_amdgcn_global_load_lds(
                    (const __attribute__((address_space(1))) unsigned int*)
                        (ab + (size_t)(tid + 256 * j) * 8), d, 16, 0, 0);
            }
        }
        const unsigned short* bb = btile + (size_t)kt * 4096;
#pragma unroll
        for (int j = 0; j < 2; ++j) {
            __attribute__((address_space(3))) unsigned int* d =
                (__attribute__((address_space(3))) unsigned int*)(Bd + (wave * 64 + 256 * j) * 8);
            __builtin_amdgcn_global_load_lds(
                (const __attribute__((address_space(1))) unsigned int*)
                    (bb + (size_t)(tid + 256 * j) * 8), d, 16, 0, 0);
        }
    };

    stage(0, 0);
    __syncthreads();
    for (int kt = 0; kt < KT; ++kt) {
        const int cur = kt & 1;
        if (kt + 1 < KT) stage(kt + 1, cur ^ 1);   // prefetch overlaps compute below
        const unsigned short* Ar = AsB + cur * 4096;
        const unsigned short* Br = BsB + cur * 4096;
        bf16x8 afr[4], bfr[4];
#pragma unroll
        for (int mt = 0; mt < 4; ++mt) {
            int rw = wm + mt * 16 + mcol;
            int p  = quad ^ ((rw & 3) ^ ((rw >> 2) & 3));
            afr[mt] = *(const bf16x8*)(Ar + (rw * 4 + p) * 8);
        }
#pragma unroll
        for (int nt = 0; nt < 4; ++nt) {
            int rw = wn + nt * 16 + mcol;
            int p  = quad ^ ((rw & 3) ^ ((rw >> 2) & 3));
            bfr[nt] = *(const bf16x8*)(Br + (rw * 4 + p) * 8);
        }
#pragma unroll
        for (int mt = 0; mt < 4; ++mt)
#pragma unroll
            for (int nt = 0; nt < 4; ++nt)
                acc[mt][nt] = __builtin_amdgcn_mfma_f32_16x16x32_bf16(
                    afr[mt], bfr[nt], acc[mt][nt], 0, 0, 0);
        __syncthreads();
    }

    // ---- epilogue: bf16 C-tile via LDS (XOR swizzle), 128 B/thread stores ----
    unsigned short* Ct = smem;   // 32 KB = 128*128 ushort
#pragma unroll
    for (int mt = 0; mt < 4; ++mt) {
        const int rl = wm + mt * 16 + quad * 4;
        float4 ts = make_float4(1.f, 1.f, 1.f, 1.f);
        if (EPI == 1) ts = *(const float4*)&rowscale[tile_m + rl];
        const float tsv[4] = {ts.x, ts.y, ts.z, ts.w};
#pragma unroll
        for (int nt = 0; nt < 4; ++nt) {
            const int cl = wn + nt * 16 + mcol;
            float bv = 0.0f;
            if (EPI == 1) {
                int col = tile_n + cl;
                bv = (col < 3 * HDIM) ? b_iou[col] : b_f[col - 3 * HDIM];
            }
#pragma unroll
            for (int r = 0; r < 4; ++r) {
                int row = rl + r;
                int g   = (cl >> 3) ^ (row & 7);
                float v = acc[mt][nt][r];
                if (EPI == 1) v = v * tsv[r] + bv;
                Ct[row * BN + g * 8 + (cl & 7)] = f2bf(v);
            }
        }
    }
    __syncthreads();
    {
        const int row  = tid >> 1;
        const int half = tid & 1;
        unsigned short* gp = C + (size_t)(tile_m + row) * ldc + tile_n + half * 64;
#pragma unroll
        for (int v = 0; v < 8; ++v) {
            int g  = half * 8 + v;
            int gs = g ^ (row & 7);
            *(us8*)(gp + v * 8) = *(const us8*)(Ct + row * BN + gs * 8);
        }
    }
}

// leaf W-GEMM: ioux[:, :1536] = (embed[vix]*tm)@W_iou + b_iou   (768 blocks)
__global__ __launch_bounds__(256) void wgemm_k(
    const float* __restrict__ Af, const int* __restrict__ aidx,
    const float* __restrict__ rs, const unsigned short* __restrict__ Wt,
    const float* __restrict__ b_iou, const float* __restrict__ b_f,
    unsigned short* __restrict__ Cw)
{
    __shared__ __align__(16) unsigned short smem[16384];
    int m = blockIdx.x & 63, n = blockIdx.x >> 6;   // same-m ids stride 64 -> one XCD
    gemm_body<1, 1>(nullptr, Af, aidx, rs, Wt, b_iou, b_f,
                    Cw, 4 * HDIM, EPAD, EDIM, m * BM, n * BN, smem);
}

// Z-GEMM: Z = hb_prev @ [U_iou|U_f]   [8192 x 512 x 2048]  (1024 blocks)
__global__ __launch_bounds__(256) void zgemm_k(
    const unsigned short* __restrict__ At, const unsigned short* __restrict__ Ut,
    unsigned short* __restrict__ Z)
{
    __shared__ __align__(16) unsigned short smem[16384];
    int m = blockIdx.x & 63, n = blockIdx.x >> 6;
    gemm_body<0, 0>(At, nullptr, nullptr, nullptr, Ut, nullptr, nullptr,
                    Z, 4 * HDIM, HDIM, HDIM, m * BM, n * BN, smem);
}

// Combined dispatch: blocks 0..1023 = W-GEMM for level l-1 (independent of the
// gate), blocks 1024..3071 = gate for level l. Hides the latency-bound gather
// kernel behind MFMA work. GM: 0 = gatefc (child-sum + fc + gates), 1 = gateleaf.
template <int GM>
__global__ __launch_bounds__(256) void gw_k(
    const float* __restrict__ Af, const int* __restrict__ aidx,
    const float* __restrict__ rs, const unsigned short* __restrict__ Wt,
    const float* __restrict__ b_iou, const float* __restrict__ b_f,
    unsigned short* __restrict__ Cw,
    const unsigned short* __restrict__ ioux, const unsigned short* __restrict__ Z,
    const int* __restrict__ cidx, const float* __restrict__ cmask,
    const float* __restrict__ c_prev,
    float* __restrict__ c_new, unsigned short* __restrict__ hb_new)
{
    __shared__ __align__(16) unsigned short smem[16384];
    const int bid = blockIdx.x;
    if (bid < 1024) {
        int m = bid & 63, n = bid >> 6;
        gemm_body<1, 1>(nullptr, Af, aidx, rs, Wt, b_iou, b_f,
                        Cw, 4 * HDIM, EPAD, EDIM, m * BM, n * BN, smem);
        return;
    }
    int t  = (bid - 1024) * 256 + threadIdx.x;   // NN*64 threads
    int n  = t >> 6;
    int j8 = (t & 63) << 3;
    const unsigned short* xr = ioux + (size_t)n * 4 * HDIM + j8;
    us8 xi = *(const us8*)xr;
    us8 xo = *(const us8*)(xr + HDIM);
    us8 xu = *(const us8*)(xr + 2 * HDIM);
    float cv[8], hv[8];
    if (GM == 1) {
#pragma unroll
        for (int j = 0; j < 8; ++j) {
            cv[j] = sigf(bf2f(xi[j])) * tanhf(bf2f(xu[j]));
            hv[j] = sigf(bf2f(xo[j])) * tanhf(cv[j]);
        }
    } else {
        us8 xf = *(const us8*)(xr + 3 * HDIM);
        float ia[8], oa[8], ua[8], xw[8], fc[8];
#pragma unroll
        for (int j = 0; j < 8; ++j) {
            ia[j] = bf2f(xi[j]); oa[j] = bf2f(xo[j]);
            ua[j] = bf2f(xu[j]); xw[j] = bf2f(xf[j]);
            fc[j] = 0.0f;
        }
        int4   ci = *(const int4*)&cidx[n * KCH];
        float4 cm = *(const float4*)&cmask[n * KCH];
        const int   cia[4] = {ci.x, ci.y, ci.z, ci.w};
        const float cma[4] = {cm.x, cm.y, cm.z, cm.w};
#pragma unroll
        for (int k = 0; k < KCH; ++k) {
            const float m = cma[k];
            const unsigned short* zr = Z + (size_t)cia[k] * 4 * HDIM + j8;
            us8 zi = *(const us8*)zr;
            us8 zo = *(const us8*)(zr + HDIM);
            us8 zu = *(const us8*)(zr + 2 * HDIM);
            us8 zf = *(const us8*)(zr + 3 * HDIM);
            const float* cpr = c_prev + (size_t)cia[k] * HDIM + j8;
            float4 ca = *(const float4*)cpr;
            float4 cb = *(const float4*)(cpr + 4);
            const float cp[8] = {ca.x, ca.y, ca.z, ca.w, cb.x, cb.y, cb.z, cb.w};
#pragma unroll
            for (int j = 0; j < 8; ++j) {
                ia[j] += m * bf2f(zi[j]);
                oa[j] += m * bf2f(zo[j]);
                ua[j] += m * bf2f(zu[j]);
                fc[j] += sigf(xw[j] + m * bf2f(zf[j])) * m * cp[j];
            }
        }
#pragma unroll
        for (int j = 0; j < 8; ++j) {
            cv[j] = sigf(ia[j]) * tanhf(ua[j]) + fc[j];
            hv[j] = sigf(oa[j]) * tanhf(cv[j]);
        }
    }
    *(float4*)(c_new + (size_t)n * HDIM + j8)     = make_float4(cv[0], cv[1], cv[2], cv[3]);
    *(float4*)(c_new + (size_t)n * HDIM + j8 + 4) = make_float4(cv[4], cv[5], cv[6], cv[7]);
    us8 hb;
#pragma unroll
    for (int j = 0; j < 8; ++j) hb[j] = f2bf(hv[j]);
    *(us8*)(hb_new + tidx(n, j8, HDIM / 32)) = hb;
}

// final level (l=0): gatefc writing fp32 h to d_out only
__global__ __launch_bounds__(256) void gatelast_k(
    const unsigned short* __restrict__ ioux, const unsigned short* __restrict__ Z,
    const int* __restrict__ cidx, const float* __restrict__ cmask,
    const float* __restrict__ c_prev, float* __restrict__ h_out)
{
    int t  = blockIdx.x * 256 + threadIdx.x;
    int n  = t >> 6;
    int j8 = (t & 63) << 3;
    const unsigned short* xr = ioux + (size_t)n * 4 * HDIM + j8;
    us8 xi = *(const us8*)xr;
    us8 xo = *(const us8*)(xr + HDIM);
    us8 xu = *(const us8*)(xr + 2 * HDIM);
    us8 xf = *(const us8*)(xr + 3 * HDIM);
    float ia[8], oa[8], ua[8], xw[8], fc[8];
#pragma unroll
    for (int j = 0; j < 8; ++j) {
        ia[j] = bf2f(xi[j]); oa[j] = bf2f(xo[j]);
        ua[j] = bf2f(xu[j]); xw[j] = bf2f(xf[j]);
        fc[j] = 0.0f;
    }
    int4   ci = *(const int4*)&cidx[n * KCH];
    float4 cm = *(const float4*)&cmask[n * KCH];
    const int   cia[4] = {ci.x, ci.y, ci.z, ci.w};
    const float cma[4] = {cm.x, cm.y, cm.z, cm.w};
#pragma unroll
    for (int k = 0; k < KCH; ++k) {
        const float m = cma[k];
        const unsigned short* zr = Z + (size_t)cia[k] * 4 * HDIM + j8;
        us8 zi = *(const us8*)zr;
        us8 zo = *(const us8*)(zr + HDIM);
        us8 zu = *(const us8*)(zr + 2 * HDIM);
        us8 zf = *(const us8*)(zr + 3 * HDIM);
        const float* cpr = c_prev + (size_t)cia[k] * HDIM + j8;
        float4 ca = *(const float4*)cpr;
        float4 cb = *(const float4*)(cpr + 4);
        const float cp[8] = {ca.x, ca.y, ca.z, ca.w, cb.x, cb.y, cb.z, cb.w};
#pragma unroll
        for (int j = 0; j < 8; ++j) {
            ia[j] += m * bf2f(zi[j]);
            oa[j] += m * bf2f(zo[j]);
            ua[j] += m * bf2f(zu[j]);
            fc[j] += sigf(xw[j] + m * bf2f(zf[j])) * m * cp[j];
        }
    }
#pragma unroll
    for (int j = 0; j < 8; ++j) {
        float c = sigf(ia[j]) * tanhf(ua[j]) + fc[j];
        fc[j] = sigf(oa[j]) * tanhf(c);      // reuse as h
    }
    *(float4*)(h_out + (size_t)n * HDIM + j8)     = make_float4(fc[0], fc[1], fc[2], fc[3]);
    *(float4*)(h_out + (size_t)n * HDIM + j8 + 4) = make_float4(fc[4], fc[5], fc[6], fc[7]);
}

extern "C" void kernel_launch(void* const* d_in, const int* in_sizes, int n_in,
                              void* d_out, int out_size, void* d_ws, size_t ws_size,
                              hipStream_t stream)
{
    const int*   vocab_ix   = (const int*)d_in[0];     // [L,N]
    const int*   child_idx  = (const int*)d_in[1];     // [L,N,K]
    const float* token_mask = (const float*)d_in[2];   // [L,N]
    const float* child_mask = (const float*)d_in[3];   // [L,N,K]
    const float* embed      = (const float*)d_in[4];   // [V,E] f32
    const float* W_iou      = (const float*)d_in[5];   // [E,3H]
    const float* U_iou      = (const float*)d_in[6];   // [H,3H]
    const float* b_iou      = (const float*)d_in[7];   // [3H]
    const float* W_f        = (const float*)d_in[8];   // [E,H]
    const float* U_f        = (const float*)d_in[9];   // [H,H]
    const float* b_f        = (const float*)d_in[10];  // [H]
    float* out = (float*)d_out;                        // [N,H] level-0 h

    // ---- workspace (~154 MB live < 256 MB L3) ----
    float* ws = (float*)d_ws;
    float* c0 = ws;                                    // [N,H] f32
    float* c1 = c0 + (size_t)NN * HDIM;                // [N,H] f32
    unsigned short* usb  = (unsigned short*)(c1 + (size_t)NN * HDIM);
    unsigned short* hb0  = usb;                                 // [N,H] bf16 tiled
    unsigned short* hb1  = hb0 + (size_t)NN * HDIM;             // [N,H] bf16 tiled
    unsigned short* iob0 = hb1 + (size_t)NN * HDIM;             // [N,4H] bf16 rm
    unsigned short* iob1 = iob0 + (size_t)NN * 4 * HDIM;        // [N,4H] bf16 rm
    unsigned short* Z    = iob1 + (size_t)NN * 4 * HDIM;        // [N,4H] bf16 rm
    unsigned short* Wt   = Z + (size_t)NN * 4 * HDIM;           // [2048,EPAD] tiled
    unsigned short* Ut   = Wt + (size_t)4 * HDIM * EPAD;        // [2048,HDIM] tiled

    dim3 blk(256);
    wconv_all_k<<<dim3((2048 * EPAD + 2048 * HDIM) / 256), blk, 0, stream>>>(
        W_iou, W_f, U_iou, U_f, Wt, Ut);

    unsigned short* bbuf[2] = { hb0, hb1 };
    float*          cbuf[2] = { c0,  c1  };
    unsigned short* iob[2]  = { iob0, iob1 };

    // leaf: W(5) -> iob[1]  (iou cols only, 12 N-tiles)
    wgemm_k<<<dim3(64 * 12), blk, 0, stream>>>(
        embed, vocab_ix + (size_t)5 * NN, token_mask + (size_t)5 * NN,
        Wt, b_iou, b_f, iob[1]);

    // level 5 gate (leaf) fused with W(4); states(5) -> buf 0
    gw_k<1><<<dim3(3072), blk, 0, stream>>>(
        embed, vocab_ix + (size_t)4 * NN, token_mask + (size_t)4 * NN,
        Wt, b_iou, b_f, iob[0],
        iob[1], nullptr, nullptr, nullptr, nullptr,
        cbuf[0], bbuf[0]);

    for (int l = 4; l >= 1; --l) {
        const int pn = (5 - l) & 1;        // new state idx (level l)
        const int pp = (4 - l) & 1;        // prev state idx (level l+1)
        // Z = h(l+1) @ [U_iou|U_f]
        zgemm_k<<<dim3(1024), blk, 0, stream>>>(bbuf[pp], Ut, Z);
        // gate(l) + W(l-1)
        gw_k<0><<<dim3(3072), blk, 0, stream>>>(
            embed, vocab_ix + (size_t)(l - 1) * NN, token_mask + (size_t)(l - 1) * NN,
            Wt, b_iou, b_f, iob[(l - 1) & 1],
            iob[l & 1], Z,
            child_idx + (size_t)l * NN * KCH, child_mask + (size_t)l * NN * KCH,
            cbuf[pp], cbuf[pn], bbuf[pn]);
    }

    // level 0: Z from h(1) (state idx (5-1)&1 = 0), then final gate -> out
    zgemm_k<<<dim3(1024), blk, 0, stream>>>(bbuf[0], Ut, Z);
    gatelast_k<<<dim3(2048), blk, 0, stream>>>(
        iob[0], Z, child_idx, child_mask, cbuf[0], out);
}